// Round 10
// baseline (224.460 us; speedup 1.0000x reference)
//
#include <hip/hip_runtime.h>
#include <hip/hip_bf16.h>

typedef __bf16 bf16;
typedef __attribute__((ext_vector_type(4))) __bf16 bf16x4;
typedef __attribute__((ext_vector_type(8))) __bf16 bf16x8;
typedef __attribute__((ext_vector_type(4))) float floatx4;

#define NSLOT 32   // rowsum partial slots per row: 32 n-blocks (BN=64, 1 wave-col each)

// async global->LDS, 16B per lane. LDS dest is wave-uniform base + lane*16 (HW-fixed);
// the GLOBAL source chunk is swizzled so LDS frag reads are conflict-free (R5/R12: conflicts 0).
__device__ __forceinline__ void gl_lds16(const bf16* g, bf16* l) {
    __builtin_amdgcn_global_load_lds(
        (const __attribute__((address_space(1))) unsigned int*)g,
        (__attribute__((address_space(3))) unsigned int*)l,
        16, 0, 0);
}

// 4(m) x 2(n) supertile swizzle: consecutive dispatch ids share A/B bands (L2 locality).
// Requires gridDim.x % 4 == 0 and gridDim.y % 2 == 0. Bijective on the grid.
__device__ __forceinline__ void swizzle_mn(int& bm, int& bn) {
    int gx = gridDim.x;
    int f  = blockIdx.y * gx + blockIdx.x;
    int st = f >> 3, r = f & 7;
    int mgroups = gx >> 2;
    bm = (st % mgroups) * 4 + (r & 3);
    bn = (st / mgroups) * 2 + (r >> 2);
}

// ---------------------------------------------------------------- x fp32 [R,C] -> xb bf16 [R,C] AND xt bf16 [C,R]
// W-transpose merged in (z == B handles W -> wt; whole blocks branch, block-uniform syncs).
__global__ __launch_bounds__(256) void cast_both(const float* __restrict__ in,
                                                 bf16* __restrict__ outn,
                                                 bf16* __restrict__ outt,
                                                 int R, int C, int B,
                                                 const float* __restrict__ Wm,
                                                 bf16* __restrict__ wt) {
    __shared__ float tile[64][65];
    const int bz = blockIdx.z;
    const int cl = (threadIdx.x & 15) * 4;   // col offset within tile
    const int rw = threadIdx.x >> 4;         // 0..15

    if (bz == B) {                            // W path: 512x512 fp32 -> wt bf16 [D,D] transposed
        if (blockIdx.x >= 8 || blockIdx.y >= 8) return;   // block-uniform early exit
        const int r0 = blockIdx.x * 64, c0 = blockIdx.y * 64;
#pragma unroll
        for (int it = 0; it < 4; ++it) {
            const int r = rw + it * 16;
            floatx4 v = *(const floatx4*)&Wm[(long long)(r0 + r) * 512 + c0 + cl];
            tile[r][cl + 0] = v[0]; tile[r][cl + 1] = v[1];
            tile[r][cl + 2] = v[2]; tile[r][cl + 3] = v[3];
        }
        __syncthreads();
#pragma unroll
        for (int it = 0; it < 4; ++it) {
            const int c = rw + it * 16;
            bf16x4 b;
            b[0] = (bf16)tile[cl + 0][c]; b[1] = (bf16)tile[cl + 1][c];
            b[2] = (bf16)tile[cl + 2][c]; b[3] = (bf16)tile[cl + 3][c];
            *(bf16x4*)&wt[(long long)(c0 + c) * 512 + r0 + cl] = b;
        }
        return;
    }

    in   += (long long)bz * R * C;
    outn += (long long)bz * R * C;
    outt += (long long)bz * R * C;
    const int r0 = blockIdx.x * 64, c0 = blockIdx.y * 64;
#pragma unroll
    for (int it = 0; it < 4; ++it) {
        const int r = rw + it * 16;
        floatx4 v = *(const floatx4*)&in[(long long)(r0 + r) * C + c0 + cl];
        bf16x4 b; b[0] = (bf16)v[0]; b[1] = (bf16)v[1]; b[2] = (bf16)v[2]; b[3] = (bf16)v[3];
        *(bf16x4*)&outn[(long long)(r0 + r) * C + c0 + cl] = b;
        tile[r][cl + 0] = v[0]; tile[r][cl + 1] = v[1];
        tile[r][cl + 2] = v[2]; tile[r][cl + 3] = v[3];
    }
    __syncthreads();
#pragma unroll
    for (int it = 0; it < 4; ++it) {
        const int c = rw + it * 16;          // original col = outt row
        bf16x4 b;
        b[0] = (bf16)tile[cl + 0][c]; b[1] = (bf16)tile[cl + 1][c];
        b[2] = (bf16)tile[cl + 2][c]; b[3] = (bf16)tile[cl + 3][c];
        *(bf16x4*)&outt[(long long)(c0 + c) * R + r0 + cl] = b;
    }
}

// ---------------------------------------------------------------- rpart [rows][NSLOT] -> rinv [rows]
// R17: softmax denominators reduced ONCE here instead of per-PV-block LDS prologue. Frees PV's
// rs[] LDS (all GEMMs -> exactly 40 KB) and removes 8 VMEM loads from PV's vmcnt stream.
__global__ __launch_bounds__(256) void rowsum_inv(const float* __restrict__ rpart,
                                                  float* __restrict__ rinv, int rows) {
    const int r = blockIdx.x * 256 + threadIdx.x;
    if (r >= rows) return;
    const float4* p = (const float4*)(rpart + (long long)r * NSLOT);
    float s = 0.f;
#pragma unroll
    for (int c = 0; c < NSLOT / 4; ++c) {
        float4 v = p[c];
        s += (v.x + v.y) + (v.z + v.w);
    }
    rinv[r] = 1.0f / s;
}

// tanh via one exp + one rcp; exact saturation at +-1. (R7: poly outer-exp regressed; keep __expf.)
__device__ __forceinline__ float fast_tanh(float v) {
    float e = __expf(2.0f * v);
    return 1.0f - 2.0f / (e + 1.0f);
}

// ---------------------------------------------------------------- 256(M)x64(N) tile, 512 thr, BK=32
// R17: cross the 64-VGPR occupancy cliff. m69: waves/CU = 32 only at <=64 VGPR; 65-128 -> 16.
// All our kernels ran ~72 unified (40 arch + 32 acc) -> pinned at 12-16 waves/CU, which is the
// TLP starvation behind the ~480 TF wall (6 schedule variants all null; 512-thr raised occupancy
// 26->36% and gave the only win so far). This round: NI=2 (acc 32) + j-split compute (only 2 bfr
// live) + __launch_bounds__(512,8) forcing <=64 VGPR; LDS exactly 40 KB (no rs[]) -> 4 blocks/CU
// = 32 waves/CU capacity.
// MODE 0 (proj): bf16 C.  MODE 1 (scores): bf16 exp(tanh(v)) + rowsum partials.
// MODE 2 (PV): fp32 v * rinv[row]  (rpart arg = precomputed rinv).
template <int MODE>
__global__ __launch_bounds__(512, 8) void gemm512(const bf16* __restrict__ A,
                                                  const bf16* __restrict__ Bm,
                                                  void* __restrict__ Cout,
                                                  float* __restrict__ rpart,
                                                  int M, int N, int K,
                                                  long long batchA, long long batchB,
                                                  long long batchC, long long batchR) {
    const long long bz = blockIdx.z;
    A  += bz * batchA;
    Bm += bz * batchB;

    __shared__ bf16 As[2][256 * 32];   // 2 x 16 KB
    __shared__ bf16 Bs[2][64 * 32];    // 2 x 4 KB   -> total 40960 B, 4 blocks/CU

    const int t    = threadIdx.x;      // 0..511
    const int lane = t & 63;
    const int w    = t >> 6;           // 0..7 : M block of 32 rows
    const int quad = lane >> 4;
    const int l16  = lane & 15;

    int bm, bn;
    swizzle_mn(bm, bn);
    const int m0 = bm * 256;
    const int n0 = bn * 64;

    floatx4 acc[2][4] = {};

    // staging: thread t covers row srow (A: +128 on 2nd instr), global chunk (t&3)^((t>>3)&3).
    const int srow = t >> 2;                         // 0..127
    const int sch  = (((t & 3) ^ ((t >> 3) & 3))) * 8;
    const bf16* Abase = A + (long long)(m0 + srow) * K + sch;
    const bf16* Bbase = Bm + (long long)(n0 + srow) * K + sch;
    const long long r128 = 128LL * K;

    // frag reads: logical chunk quad after inverse swizzle (2-way max aliasing = free, m136)
    const int rdch = (quad ^ ((l16 >> 1) & 3)) * 8;

    auto stage = [&](int buf, int k0) {
        gl_lds16(Abase + k0,        &As[buf][t * 8]);
        gl_lds16(Abase + k0 + r128, &As[buf][t * 8 + 4096]);
        if (t < 256) gl_lds16(Bbase + k0, &Bs[buf][t * 8]);   // 64x32: waves 0-3 (wave-uniform)
    };

    // j-split compute: af[2] + bfr[2] live (24 regs with acc 32) to stay under the 64-VGPR cliff
    auto compute = [&](int buf) {
        bf16x8 af0 = *(const bf16x8*)(&As[buf][(w * 32 + l16) * 32 + rdch]);
        bf16x8 af1 = *(const bf16x8*)(&As[buf][(w * 32 + 16 + l16) * 32 + rdch]);
#pragma unroll
        for (int jh = 0; jh < 2; ++jh) {
            bf16x8 b0 = *(const bf16x8*)(&Bs[buf][(jh * 32 + l16) * 32 + rdch]);
            bf16x8 b1 = *(const bf16x8*)(&Bs[buf][(jh * 32 + 16 + l16) * 32 + rdch]);
            acc[0][jh * 2 + 0] = __builtin_amdgcn_mfma_f32_16x16x32_bf16(af0, b0, acc[0][jh * 2 + 0], 0, 0, 0);
            acc[0][jh * 2 + 1] = __builtin_amdgcn_mfma_f32_16x16x32_bf16(af0, b1, acc[0][jh * 2 + 1], 0, 0, 0);
            acc[1][jh * 2 + 0] = __builtin_amdgcn_mfma_f32_16x16x32_bf16(af1, b0, acc[1][jh * 2 + 0], 0, 0, 0);
            acc[1][jh * 2 + 1] = __builtin_amdgcn_mfma_f32_16x16x32_bf16(af1, b1, acc[1][jh * 2 + 1], 0, 0, 0);
        }
    };

    const int NT = K >> 5;
    stage(0, 0);
    __syncthreads();
    for (int it = 0; it < NT; ++it) {
        const int buf = it & 1;
        if (it + 1 < NT) stage(buf ^ 1, (it + 1) << 5);   // prefetch in flight during compute
        compute(buf);
        __syncthreads();
    }

    if (MODE == 1) {
        bf16* Cg = (bf16*)Cout + bz * batchC;
        const int slot = bn;            // 32 n-blocks, 1 wave-col each -> slot = bn
#pragma unroll
        for (int i = 0; i < 2; ++i)
#pragma unroll
            for (int r = 0; r < 4; ++r) {
                long long row = m0 + w * 32 + i * 16 + quad * 4 + r;
                float s = 0.f;
#pragma unroll
                for (int j = 0; j < 4; ++j) {
                    float v = __expf(fast_tanh(acc[i][j][r]));
                    s += v;
                    Cg[row * (long long)N + (n0 + j * 16 + l16)] = (bf16)v;
                }
#pragma unroll
                for (int msk = 1; msk < 16; msk <<= 1) s += __shfl_xor(s, msk);
                if (l16 == 0)
                    rpart[(bz * batchR + row) * NSLOT + slot] = s;   // plain store, race-free
            }
    } else if (MODE == 2) {
        float* Og = (float*)Cout + bz * batchC;
        const float* rinv = rpart;      // precomputed 1/rowsum, [batchR] per batch
#pragma unroll
        for (int i = 0; i < 2; ++i)
#pragma unroll
            for (int r = 0; r < 4; ++r) {
                int rl = w * 32 + i * 16 + quad * 4 + r;
                float inv = rinv[bz * batchR + m0 + rl];
                long long row = m0 + rl;
#pragma unroll
                for (int j = 0; j < 4; ++j)
                    Og[row * (long long)N + (n0 + j * 16 + l16)] = acc[i][j][r] * inv;
            }
    } else {
        bf16* Cg = (bf16*)Cout + bz * batchC;
#pragma unroll
        for (int i = 0; i < 2; ++i)
#pragma unroll
            for (int r = 0; r < 4; ++r) {
                long long row = m0 + w * 32 + i * 16 + quad * 4 + r;
#pragma unroll
                for (int j = 0; j < 4; ++j)
                    Cg[row * (long long)N + (n0 + j * 16 + l16)] = (bf16)acc[i][j][r];
            }
    }
}

// ----------------------------------------------------------------
extern "C" void kernel_launch(void* const* d_in, const int* in_sizes, int n_in,
                              void* d_out, int out_size, void* d_ws, size_t ws_size,
                              hipStream_t stream) {
    const int B = 8, S = 2048, D = 512;
    const float* x = (const float*)d_in[0];
    const float* W = (const float*)d_in[1];
    float* out = (float*)d_out;

    const size_t nx = (size_t)B * S * D;
    const size_t nw = (size_t)D * D;

    char* ws = (char*)d_ws;
    auto al = [](size_t v) { return (v + 255) & ~(size_t)255; };
    size_t off = 0;
    bf16* xb = (bf16*)(ws + off); off = al(off + nx * 2);          // x bf16 [B,S,D]
    bf16* xt = (bf16*)(ws + off); off = al(off + nx * 2);          // x^T bf16 [B,D,S]
    bf16* pb = (bf16*)(ws + off); off = al(off + nx * 2);          // proj bf16 [B,S,D]
    bf16* wt = (bf16*)(ws + off); off = al(off + nw * 2);          // W^T bf16 [D,D]
    float* rpart = (float*)(ws + off); off = al(off + (size_t)B * S * NSLOT * 4);  // rowsum partials
    float* rinv  = (float*)(ws + off); off = al(off + (size_t)B * S * 4);          // 1/rowsum
    bf16* sb = (bf16*)(ws + off);                                  // P_unnorm bf16
    const size_t full_need = off + (size_t)B * S * S * 2;
    const bool batched = (ws_size >= full_need);

    // casts: x -> xb,xt (z = 0..B-1) and W -> wt (z = B)
    { dim3 g(S / 64, D / 64, B + 1); cast_both<<<g, 256, 0, stream>>>(x, xb, xt, S, D, B, W, wt); }

    // proj: pb[BS,D] = xb @ wt^T   (256x64 tiles, grid 64x8 = 512 blocks)
    {
        dim3 g(B * S / 256, D / 64, 1);
        gemm512<0><<<g, 512, 0, stream>>>(xb, wt, (void*)pb, nullptr, B * S, D, D, 0, 0, 0, 0);
    }

    const long long sd = (long long)S * D;
    const long long ss = (long long)S * S;

    if (batched) {
        // P_un = exp(tanh(pb @ xb^T)), rowsum partials   (256x64 tiles, grid 8x32x8 = 2048)
        dim3 g2(S / 256, S / 64, B);
        gemm512<1><<<g2, 512, 0, stream>>>(pb, xb, (void*)sb, rpart, S, S, D, sd, sd, ss, S);
        // rowsum reduce: rpart -> rinv  (B*S rows)
        rowsum_inv<<<dim3(B * S / 256), 256, 0, stream>>>(rpart, rinv, B * S);
        // out = (P_un @ xt^T) * rinv                     (256x64 tiles, grid 8x8x8 = 512)
        dim3 g4(S / 256, D / 64, B);
        gemm512<2><<<g4, 512, 0, stream>>>(sb, xt, (void*)out, rinv, S, D, S, ss, sd, sd, S);
    } else {
        for (int b = 0; b < B; ++b) {
            dim3 g2(S / 256, S / 64, 1);
            gemm512<1><<<g2, 512, 0, stream>>>(pb + (size_t)b * sd, xb + (size_t)b * sd,
                                               (void*)sb, rpart + (size_t)b * S * NSLOT,
                                               S, S, D, 0, 0, 0, S);
            rowsum_inv<<<dim3(S / 256), 256, 0, stream>>>(rpart + (size_t)b * S * NSLOT,
                                                          rinv + (size_t)b * S, S);
            dim3 g4(S / 256, D / 64, 1);
            gemm512<2><<<g4, 512, 0, stream>>>(sb, xt + (size_t)b * sd,
                                               (void*)(out + (size_t)b * sd), rinv + (size_t)b * S,
                                               S, D, S, 0, 0, 0, S);
        }
    }
}